// Round 16
// baseline (144.592 us; speedup 1.0000x reference)
//
#include <hip/hip_runtime.h>
#include <cstdint>
#include <cstddef>

typedef __attribute__((ext_vector_type(8))) short bf16x8;
typedef __attribute__((ext_vector_type(4))) float f32x4;
typedef __attribute__((ext_vector_type(4))) int   i32x4;

#define C_CH   256
#define NBOX   512      // B*N
#define FCDIM  1024
#define K1     12544    // C*7*7
#define OUTC   93
#define Z1     28       // split-K for FC1 (KC = 448, 14 steps, 896 blocks) -- isolated A/B vs 14
#define Z2     8        // split-K for FC2 (KC = 128, 4 steps)

__device__ __forceinline__ unsigned short f2bf(float f) {
    unsigned u = __float_as_uint(f);
    u += 0x7fffu + ((u >> 16) & 1u);      // RNE
    return (unsigned short)(u >> 16);
}
__device__ __forceinline__ float bf2f(short s) {
    return __uint_as_float((unsigned)(unsigned short)s << 16);
}
__device__ __forceinline__ void stage16(const void* g, const void* l) {
    __builtin_amdgcn_global_load_lds(
        (const __attribute__((address_space(1))) void*)g,
        (__attribute__((address_space(3))) void*)l, 16, 0, 0);
}

// ---------------- merged streaming: feature transpose (blocks 0..1359) + weight casts ----------
__global__ __launch_bounds__(256) void stream_prep_kernel(
    const float* __restrict__ f0, const float* __restrict__ f1,
    const float* __restrict__ f2, const float* __restrict__ f3,
    short* __restrict__ g0, short* __restrict__ g1,
    short* __restrict__ g2, short* __restrict__ g3,
    const float* __restrict__ w1f, short* __restrict__ w1b,
    const float* __restrict__ w2f, short* __restrict__ w2b)
{
    __shared__ short tile[128 * 66];
    int id = blockIdx.x;
    int t  = threadIdx.x;

    if (id >= 1360) {                      // ---- streaming cast path ----
        int cb = id - 1360;
        const float* src; short* dst;
        if (cb < 6272) { src = w1f; dst = w1b; }
        else           { src = w2f; dst = w2b; cb -= 6272; }
        size_t i = ((size_t)cb * 256 + t) * 8;
        const float4* p = (const float4*)(src + i);
        float4 a = p[0], b = p[1];
        union { unsigned short s[8]; i32x4 v; } u;
        u.s[0] = f2bf(a.x); u.s[1] = f2bf(a.y); u.s[2] = f2bf(a.z); u.s[3] = f2bf(a.w);
        u.s[4] = f2bf(b.x); u.s[5] = f2bf(b.y); u.s[6] = f2bf(b.z); u.s[7] = f2bf(b.w);
        *(i32x4*)(dst + i) = u.v;
        return;
    }

    const float* src; short* dst; int HW, nx;
    if (id < 1024)      { src = f0; dst = g0; HW = 16384; nx = 128; }
    else if (id < 1280) { id -= 1024; src = f1; dst = g1; HW = 4096; nx = 32; }
    else if (id < 1344) { id -= 1280; src = f2; dst = g2; HW = 1024; nx = 8; }
    else                { id -= 1344; src = f3; dst = g3; HW = 256;  nx = 2; }
    int xb = id % nx;  int rest = id / nx;
    int cy = rest & 3; int b = rest >> 2;
    int p0 = xb * 128, c0 = cy * 64;

    const float* s = src + ((size_t)b * C_CH + c0) * HW + p0;
    #pragma unroll
    for (int it = 0; it < 16; ++it) {
        int slot = it * 256 + t;           // over [64 ch][64 pixel-pairs]
        int cl = slot >> 6;
        int pp = slot & 63;
        float2 v = *(const float2*)(s + (size_t)cl * HW + pp * 2);
        tile[(pp * 2) * 66 + cl]     = (short)f2bf(v.x);
        tile[(pp * 2 + 1) * 66 + cl] = (short)f2bf(v.y);
    }
    __syncthreads();
    short* d = dst + ((size_t)b * HW + p0) * C_CH + c0;
    #pragma unroll
    for (int it = 0; it < 16; ++it) {
        int pl = it * 8 + (t >> 5);        // 0..127
        int c2 = (t & 31) * 2;
        *(unsigned*)(d + (size_t)pl * C_CH + c2) = *(const unsigned*)&tile[pl * 66 + c2];
    }
}

// ---------------- ROI align: channel-last bf16 features, one block per box ----------------
__global__ __launch_bounds__(512) void roi_kernel(
    const short* __restrict__ g0, const short* __restrict__ g1,
    const short* __restrict__ g2, const short* __restrict__ g3,
    const float* __restrict__ bbox, const int* __restrict__ aid,
    short* __restrict__ pooled)
{
    int bn  = blockIdx.x;           // b*256 + n
    int b   = bn >> 8;
    int t   = threadIdx.x;
    int c   = t & 255;
    int sub = t >> 8;

    __shared__ int   xo0[14], xo1[14];   // x offsets premul by C_CH
    __shared__ float wxs[14];
    __shared__ int   yo0[14], yo1[14];   // y offsets premul by H*C_CH
    __shared__ float wys[14];
    __shared__ short otile[K1];          // [c*49 + s], 25088 B

    float yb = bbox[bn*4+0], xb = bbox[bn*4+1], hb = bbox[bn*4+2], wb = bbox[bn*4+3];
    int level = aid[bn] / 3;
    const short* gsrc = (level == 0) ? g0 : (level == 1) ? g1 : (level == 2) ? g2 : g3;
    int H = 128 >> level;
    float scale = 1.0f / (float)(4 << level);
    const short* gp = gsrc + (size_t)b * H * H * C_CH;

    if (t < 14) {
        float g  = ((float)t + 0.5f) * 0.5f;
        float l0 = (xb - 0.5f*wb) * scale - 0.5f;
        float bw = wb * scale * (1.0f/7.0f);
        float v  = fminf(fmaxf(l0 + bw * g, 0.0f), (float)(H-1));
        int i0 = (int)v;
        xo0[t] = i0 * C_CH;
        xo1[t] = min(i0 + 1, H - 1) * C_CH;
        wxs[t] = v - (float)i0;
    } else if (t < 28) {
        int sy = t - 14;
        float g  = ((float)sy + 0.5f) * 0.5f;
        float t0 = (yb - 0.5f*hb) * scale - 0.5f;
        float bh = hb * scale * (1.0f/7.0f);
        float v  = fminf(fmaxf(t0 + bh * g, 0.0f), (float)(H-1));
        int i0 = (int)v;
        yo0[sy] = i0 * H * C_CH;
        yo1[sy] = min(i0 + 1, H - 1) * H * C_CH;
        wys[sy] = v - (float)i0;
    }
    __syncthreads();

    #pragma unroll 2
    for (int s = sub; s < 49; s += 2) {
        int py = s / 7, px = s - py * 7;
        float acc = 0.0f;
        #pragma unroll
        for (int i = 0; i < 2; i++) {
            int sy = 2 * py + i;
            int ry0 = yo0[sy], ry1 = yo1[sy];
            float wy = wys[sy];
            #pragma unroll
            for (int j = 0; j < 2; j++) {
                int sx = 2 * px + j;
                int cx0 = xo0[sx] + c, cx1 = xo1[sx] + c;
                float wx = wxs[sx];
                float v00 = bf2f(gp[ry0 + cx0]);
                float v01 = bf2f(gp[ry0 + cx1]);
                float v10 = bf2f(gp[ry1 + cx0]);
                float v11 = bf2f(gp[ry1 + cx1]);
                float top = v00 * (1.0f - wx) + v01 * wx;
                float bot = v10 * (1.0f - wx) + v11 * wx;
                acc += top * (1.0f - wy) + bot * wy;
            }
        }
        otile[c * 49 + s] = (short)f2bf(acc * 0.25f);
    }
    __syncthreads();

    const i32x4* srcv = (const i32x4*)otile;
    i32x4* dstv = (i32x4*)(pooled + (size_t)bn * K1);
    for (int j = t; j < (K1 * 2) / 16; j += 512)   // 1568 chunks of 16B
        dstv[j] = srcv[j];
}

// ---------------- bf16 GEMM, 128x128 tile, double-buffered global_load_lds (R7-proven) ----------
// A:[512][K] bf16, Bt:[1024][K] bf16 (K-contiguous), part:[z][512][1024] f32
// flat grid = 4 * NP, NP = 8*z; decode keeps same-B-panel blocks on one XCD (id ≡ p mod 8).
__global__ __launch_bounds__(256) void gemm_db(
    const short* __restrict__ A, const short* __restrict__ Bt,
    float* __restrict__ part, int K, int KC, int NP)
{
    __shared__ short As[2][4096];    // [buf][128 rows * 32 shorts]
    __shared__ short Bs[2][4096];
    int t = threadIdx.x, lane = t & 63, w = t >> 6;
    int bid = blockIdx.x;
    int p = bid % NP, m = bid / NP;
    int n = p & 7, z = p >> 3;
    int m0 = m * 128, n0 = n * 128;
    size_t k0 = (size_t)z * KC;

    // staging: wave w fills chunks {2w, 2w+1} of each matrix per step.
    int gslot = (lane & 3) * 8;           // shorts
    int lrow  = lane >> 2;
    int qa0 = 2 * w, qa1 = 2 * w + 1;
    const short* gA0 = A  + (size_t)(m0 + qa0 * 16 + lrow) * K + k0 + gslot;
    const short* gA1 = A  + (size_t)(m0 + qa1 * 16 + lrow) * K + k0 + gslot;
    const short* gB0 = Bt + (size_t)(n0 + qa0 * 16 + lrow) * K + k0 + gslot;
    const short* gB1 = Bt + (size_t)(n0 + qa1 * 16 + lrow) * K + k0 + gslot;
    const short* lA0 = &As[0][qa0 * 512];
    const short* lA1 = &As[0][qa1 * 512];
    const short* lB0 = &Bs[0][qa0 * 512];
    const short* lB1 = &Bs[0][qa1 * 512];

    // fragment reads: wave quadrant (wr,wc), 4x4 16x16 subtiles
    int wr = (w >> 1) * 64, wc = (w & 1) * 64;
    int fr = lane & 15, kg = lane >> 4;
    int raoff = (wr + fr) * 32 + kg * 8;
    int rboff = (wc + fr) * 32 + kg * 8;

    int nsteps = KC >> 5;

    // prologue: stage buf 0
    stage16(gA0, lA0); stage16(gA1, lA1);
    stage16(gB0, lB0); stage16(gB1, lB1);
    __syncthreads();                      // drains vmcnt(0) before barrier

    f32x4 acc[4][4] = {};
    for (int s = 0; s < nsteps; ++s) {
        int cur = s & 1;
        if (s + 1 < nsteps) {             // issue next-tile loads BEFORE compute
            int nxt = cur ^ 1;
            int ks = (s + 1) * 32;
            stage16(gA0 + ks, lA0 + nxt * 4096);
            stage16(gA1 + ks, lA1 + nxt * 4096);
            stage16(gB0 + ks, lB0 + nxt * 4096);
            stage16(gB1 + ks, lB1 + nxt * 4096);
        }
        const short* ra = &As[cur][raoff];
        const short* rb = &Bs[cur][rboff];
        bf16x8 af[4], bm[4];
        #pragma unroll
        for (int i = 0; i < 4; i++) af[i] = *(const bf16x8*)(ra + i * 512);
        #pragma unroll
        for (int j = 0; j < 4; j++) bm[j] = *(const bf16x8*)(rb + j * 512);
        #pragma unroll
        for (int i = 0; i < 4; i++)
            #pragma unroll
            for (int j = 0; j < 4; j++)
                acc[i][j] = __builtin_amdgcn_mfma_f32_16x16x32_bf16(af[i], bm[j], acc[i][j], 0, 0, 0);
        __syncthreads();                  // one barrier/step; drains staging for next iter
    }

    float* base = part + (size_t)z * NBOX * FCDIM;
    #pragma unroll
    for (int i = 0; i < 4; i++)
        #pragma unroll
        for (int j = 0; j < 4; j++)
            #pragma unroll
            for (int r = 0; r < 4; r++) {
                int row = m0 + wr + i * 16 + kg * 4 + r;
                int col = n0 + wc + j * 16 + fr;
                base[(size_t)row * FCDIM + col] = acc[i][j][r];
            }
}

// ---------------- BN stage 1: sum split-K partials, per-block column stats ----------------
template<int NZ>
__global__ __launch_bounds__(256) void bn_stats1(
    const float* __restrict__ part, float* __restrict__ xsum, float* __restrict__ pstat)
{
    int tc = threadIdx.x & 63;
    int tr = threadIdx.x >> 6;
    int c  = blockIdx.x * 64 + tc;
    int r0 = blockIdx.y * 32;
    const size_t P = (size_t)NBOX * FCDIM;

    float s = 0.0f, q = 0.0f;
    #pragma unroll
    for (int rr = 0; rr < 8; rr++) {
        size_t o = (size_t)(r0 + tr + rr * 4) * FCDIM + c;
        float x = 0.0f;
        #pragma unroll
        for (int z = 0; z < NZ; z++) x += part[o + (size_t)z * P];
        xsum[o] = x;
        s += x; q += x * x;
    }
    __shared__ float Ss[4][64], Sq[4][64];
    Ss[tr][tc] = s; Sq[tr][tc] = q;
    __syncthreads();
    if (tr == 0) {
        float S = Ss[0][tc] + Ss[1][tc] + Ss[2][tc] + Ss[3][tc];
        float Q = Sq[0][tc] + Sq[1][tc] + Sq[2][tc] + Sq[3][tc];
        pstat[blockIdx.y * FCDIM + c] = S;
        pstat[16 * FCDIM + blockIdx.y * FCDIM + c] = Q;
    }
}

// ---------------- BN stage 2: finalize per-column scale/shift ----------------
__global__ __launch_bounds__(256) void bn_stats2(
    const float* __restrict__ pstat, const float* __restrict__ g,
    const float* __restrict__ be, float* __restrict__ scsh)
{
    int c = blockIdx.x * 256 + threadIdx.x;   // grid 4
    float S = 0.0f, Q = 0.0f;
    #pragma unroll
    for (int i = 0; i < 16; i++) {
        S += pstat[i * FCDIM + c];
        Q += pstat[16 * FCDIM + i * FCDIM + c];
    }
    float mu  = S * (1.0f / NBOX);
    float var = Q * (1.0f / NBOX) - mu * mu;
    float a = g[c] * rsqrtf(var + 1e-5f);
    scsh[c]         = a;
    scsh[FCDIM + c] = be[c] - mu * a;
}

// ---------------- BN apply (BN1): normalize + ReLU -> bf16 ----------------
__global__ __launch_bounds__(256) void bn_apply_bf(
    const float* __restrict__ xsum, const float* __restrict__ scsh,
    short* __restrict__ obf)
{
    size_t base = ((size_t)blockIdx.x * 256 + threadIdx.x) * 8;   // grid 256
    int c0 = (int)(base & (FCDIM - 1));
    float4 x0 = *(const float4*)(xsum + base);
    float4 x1 = *(const float4*)(xsum + base + 4);
    float4 a0 = *(const float4*)(scsh + c0);
    float4 a1 = *(const float4*)(scsh + c0 + 4);
    float4 b0 = *(const float4*)(scsh + FCDIM + c0);
    float4 b1 = *(const float4*)(scsh + FCDIM + c0 + 4);
    float r[8];
    r[0] = fmaxf(x0.x*a0.x + b0.x, 0.0f);
    r[1] = fmaxf(x0.y*a0.y + b0.y, 0.0f);
    r[2] = fmaxf(x0.z*a0.z + b0.z, 0.0f);
    r[3] = fmaxf(x0.w*a0.w + b0.w, 0.0f);
    r[4] = fmaxf(x1.x*a1.x + b1.x, 0.0f);
    r[5] = fmaxf(x1.y*a1.y + b1.y, 0.0f);
    r[6] = fmaxf(x1.z*a1.z + b1.z, 0.0f);
    r[7] = fmaxf(x1.w*a1.w + b1.w, 0.0f);
    union { unsigned short s[8]; i32x4 v; } u;
    #pragma unroll
    for (int i = 0; i < 8; i++) u.s[i] = f2bf(r[i]);
    *(i32x4*)(obf + base) = u.v;
}

// ---------------- fused BN2-apply + pred GEMV + bbox decode (consumes precomputed scsh) --------
__global__ __launch_bounds__(128) void bn2_pred_kernel(
    const float* __restrict__ xsum, const float* __restrict__ scsh,
    const float* __restrict__ pw, const float* __restrict__ pb,
    const float* __restrict__ bbox, const int* __restrict__ aid,
    const float* __restrict__ zp, float* __restrict__ out)
{
    int bn = blockIdx.x;
    int t  = threadIdx.x;
    __shared__ float xs[FCDIM];
    __shared__ float pr[OUTC];
    for (int i = t; i < FCDIM; i += 128)
        xs[i] = fmaxf(xsum[(size_t)bn * FCDIM + i] * scsh[i] + scsh[FCDIM + i], 0.0f);
    __syncthreads();

    float z = zp[bn];
    if (t < OUTC) {
        const float* wrow = pw + (size_t)t * FCDIM;
        float a = 0.0f;
        for (int k = 0; k < FCDIM; k += 4) {
            float4 w4 = *(const float4*)(wrow + k);
            a += xs[k] * w4.x + xs[k+1] * w4.y + xs[k+2] * w4.z + xs[k+3] * w4.w;
        }
        pr[t] = (a + pb[t]) * z;
    }
    __syncthreads();

    if (t < OUTC) {
        float y = bbox[bn*4+0], x = bbox[bn*4+1], h = bbox[bn*4+2], w = bbox[bn*4+3];
        int lvl = aid[bn] / 3;
        float st = 4.0f * exp2f((float)lvl * z);
        float o;
        if (t < 24) {
            int k = t / 6, j = t - k * 6;
            const float* d = &pr[5 + k * 6];
            switch (j) {
                case 0:  o = y + d[0] * h;  break;
                case 1:  o = x + d[1] * w;  break;
                case 2:  o = d[4] * st;     break;
                case 3:  o = h * expf(d[2]); break;
                case 4:  o = w * expf(d[3]); break;
                default: o = expf(d[5]) * st; break;
            }
        } else if (t < 29) {
            float m = pr[0];
            #pragma unroll
            for (int i = 1; i < 5; i++) m = fmaxf(m, pr[i]);
            float den = 0.0f;
            #pragma unroll
            for (int i = 0; i < 5; i++) den += expf(pr[i] - m);
            o = expf(pr[t - 24] - m) / den;
        } else if (t < 61) {
            int i = t - 29, k = i >> 3;
            const float* qq = &pr[29 + k * 8];
            float m = qq[0];
            #pragma unroll
            for (int ii = 1; ii < 8; ii++) m = fmaxf(m, qq[ii]);
            float den = 0.0f;
            #pragma unroll
            for (int ii = 0; ii < 8; ii++) den += expf(qq[ii] - m);
            o = expf(pr[t] - m) / den;
        } else {
            o = 1.0f / (1.0f + expf(-pr[t])) * 0.6f - 0.3f;
        }
        out[(size_t)bn * OUTC + t] = o;
    }
}

extern "C" void kernel_launch(void* const* d_in, const int* in_sizes, int n_in,
                              void* d_out, int out_size, void* d_ws, size_t ws_size,
                              hipStream_t stream)
{
    const float* f0   = (const float*)d_in[0];
    const float* f1   = (const float*)d_in[1];
    const float* f2   = (const float*)d_in[2];
    const float* f3   = (const float*)d_in[3];
    const float* bbox = (const float*)d_in[4];
    const int*   aid  = (const int*)d_in[5];
    const float* zp   = (const float*)d_in[6];
    const float* fc1w = (const float*)d_in[7];
    const float* bn1g = (const float*)d_in[9];
    const float* bn1b = (const float*)d_in[10];
    const float* fc2w = (const float*)d_in[11];
    const float* bn2g = (const float*)d_in[13];
    const float* bn2b = (const float*)d_in[14];
    const float* pw   = (const float*)d_in[15];
    const float* pb   = (const float*)d_in[16];
    float* out = (float*)d_out;

    // workspace layout (linear, ~145.4 MB of the 256 MiB ws; part1 region holds Z1=28 partials)
    char* ws = (char*)d_ws;
    short* pooled = (short*)(ws);                    // 12,845,056
    short* gt0    = (short*)(ws + 13631488);         // 16,777,216
    short* gt1    = (short*)(ws + 30408704);         //  4,194,304
    short* gt2    = (short*)(ws + 34603008);         //  1,048,576
    short* gt3    = (short*)(ws + 35651584);         //    262,144
    short* w1     = (short*)(ws + 36700160);         // 25,690,112
    short* w2     = (short*)(ws + 62390272);         //  2,097,152
    float* part1  = (float*)(ws + 64487424);         // Z1 * 2,097,152 = 58,720,256
    float* part2  = (float*)(ws + 123207680);        // Z2 * 2,097,152 = 16,777,216
    float* xsum   = (float*)(ws + 139984896);        //  2,097,152
    short* x1n    = (short*)(ws + 142082048);        //  1,048,576
    float* pstat  = (float*)(ws + 145227776);        //    131,072
    float* scsh   = (float*)(ws + 145358848);        //      8,192

    // 1 merged streaming launch: transpose (1360) + w1 cast (6272) + w2 cast (512)
    stream_prep_kernel<<<1360 + 6272 + 512, 256, 0, stream>>>(
        f0, f1, f2, f3, gt0, gt1, gt2, gt3, fc1w, w1, fc2w, w2);

    roi_kernel<<<NBOX, 512, 0, stream>>>(gt0, gt1, gt2, gt3, bbox, aid, pooled);

    gemm_db<<<4 * 8 * Z1, 256, 0, stream>>>(pooled, w1, part1, K1, K1 / Z1, 8 * Z1);

    bn_stats1<Z1><<<dim3(16, 16), 256, 0, stream>>>(part1, xsum, pstat);
    bn_stats2<<<4, 256, 0, stream>>>(pstat, bn1g, bn1b, scsh);
    bn_apply_bf<<<256, 256, 0, stream>>>(xsum, scsh, x1n);

    gemm_db<<<4 * 8 * Z2, 256, 0, stream>>>(x1n, w2, part2, FCDIM, FCDIM / Z2, 8 * Z2);

    bn_stats1<Z2><<<dim3(16, 16), 256, 0, stream>>>(part2, xsum, pstat);
    bn_stats2<<<4, 256, 0, stream>>>(pstat, bn2g, bn2b, scsh);

    bn2_pred_kernel<<<NBOX, 128, 0, stream>>>(xsum, scsh, pw, pb, bbox, aid, zp, out);
}

// Round 17
// 135.224 us; speedup vs baseline: 1.0693x; 1.0693x over previous
//
#include <hip/hip_runtime.h>
#include <cstdint>
#include <cstddef>

typedef __attribute__((ext_vector_type(8))) short bf16x8;
typedef __attribute__((ext_vector_type(4))) float f32x4;
typedef __attribute__((ext_vector_type(4))) int   i32x4;

#define C_CH   256
#define NBOX   512      // B*N
#define FCDIM  1024
#define K1     12544    // C*7*7
#define OUTC   93
#define Z1     14       // split-K for FC1 (KC = 896, 28 steps) -- R16 proved 28 is worse (BW-bound)
#define Z2     8        // split-K for FC2 (KC = 128, 4 steps)

__device__ __forceinline__ unsigned short f2bf(float f) {
    unsigned u = __float_as_uint(f);
    u += 0x7fffu + ((u >> 16) & 1u);      // RNE
    return (unsigned short)(u >> 16);
}
__device__ __forceinline__ float bf2f(short s) {
    return __uint_as_float((unsigned)(unsigned short)s << 16);
}
__device__ __forceinline__ void stage16(const void* g, const void* l) {
    __builtin_amdgcn_global_load_lds(
        (const __attribute__((address_space(1))) void*)g,
        (__attribute__((address_space(3))) void*)l, 16, 0, 0);
}

// ---------------- merged streaming: feature transpose (blocks 0..1359) + weight casts ----------
// R17: explicit MLP batching — R16 profile showed VGPR=20 / HBM 2.3TB/s / VALU 6% (load-latency
// serial). Cast: 32 floats/thread, 8 independent float4 loads up front. Transpose: 2 groups of
// 8 batched float2 loads. Same math, same layout, just load-batched.
__global__ __launch_bounds__(256) void stream_prep_kernel(
    const float* __restrict__ f0, const float* __restrict__ f1,
    const float* __restrict__ f2, const float* __restrict__ f3,
    short* __restrict__ g0, short* __restrict__ g1,
    short* __restrict__ g2, short* __restrict__ g3,
    const float* __restrict__ w1f, short* __restrict__ w1b,
    const float* __restrict__ w2f, short* __restrict__ w2b)
{
    __shared__ short tile[128 * 66];
    int id = blockIdx.x;
    int t  = threadIdx.x;

    if (id >= 1360) {                      // ---- cast path: 32 floats / thread ----
        int cb = id - 1360;
        const float* src; short* dst;
        if (cb < 1568) { src = w1f; dst = w1b; }      // 1568 blocks * 8192 floats = 12,845,056
        else           { src = w2f; dst = w2b; cb -= 1568; }   // 128 blocks = 1,048,576
        size_t base = ((size_t)cb * 256 + t) * 32;
        float4 v[8];
        #pragma unroll
        for (int j = 0; j < 8; j++) v[j] = *(const float4*)(src + base + j * 4);
        #pragma unroll
        for (int j = 0; j < 4; j++) {
            float4 a = v[2 * j], b = v[2 * j + 1];
            union { unsigned short s[8]; i32x4 q; } u;
            u.s[0] = f2bf(a.x); u.s[1] = f2bf(a.y); u.s[2] = f2bf(a.z); u.s[3] = f2bf(a.w);
            u.s[4] = f2bf(b.x); u.s[5] = f2bf(b.y); u.s[6] = f2bf(b.z); u.s[7] = f2bf(b.w);
            *(i32x4*)(dst + base + j * 8) = u.q;
        }
        return;
    }

    const float* src; short* dst; int HW, nx;
    if (id < 1024)      { src = f0; dst = g0; HW = 16384; nx = 128; }
    else if (id < 1280) { id -= 1024; src = f1; dst = g1; HW = 4096; nx = 32; }
    else if (id < 1344) { id -= 1280; src = f2; dst = g2; HW = 1024; nx = 8; }
    else                { id -= 1344; src = f3; dst = g3; HW = 256;  nx = 2; }
    int xb = id % nx;  int rest = id / nx;
    int cy = rest & 3; int b = rest >> 2;
    int p0 = xb * 128, c0 = cy * 64;

    const float* s = src + ((size_t)b * C_CH + c0) * HW + p0;
    #pragma unroll
    for (int g = 0; g < 2; g++) {
        float2 v[8];
        #pragma unroll
        for (int j = 0; j < 8; j++) {
            int slot = (g * 8 + j) * 256 + t;       // over [64 ch][64 pixel-pairs]
            v[j] = *(const float2*)(s + (size_t)(slot >> 6) * HW + (slot & 63) * 2);
        }
        #pragma unroll
        for (int j = 0; j < 8; j++) {
            int slot = (g * 8 + j) * 256 + t;
            int cl = slot >> 6;
            int pp = slot & 63;
            tile[(pp * 2) * 66 + cl]     = (short)f2bf(v[j].x);
            tile[(pp * 2 + 1) * 66 + cl] = (short)f2bf(v[j].y);
        }
    }
    __syncthreads();
    short* d = dst + ((size_t)b * HW + p0) * C_CH + c0;
    #pragma unroll
    for (int it = 0; it < 16; ++it) {
        int pl = it * 8 + (t >> 5);        // 0..127
        int c2 = (t & 31) * 2;
        *(unsigned*)(d + (size_t)pl * C_CH + c2) = *(const unsigned*)&tile[pl * 66 + c2];
    }
}

// ---------------- ROI align: channel-last bf16 features, one block per box ----------------
__global__ __launch_bounds__(512) void roi_kernel(
    const short* __restrict__ g0, const short* __restrict__ g1,
    const short* __restrict__ g2, const short* __restrict__ g3,
    const float* __restrict__ bbox, const int* __restrict__ aid,
    short* __restrict__ pooled)
{
    int bn  = blockIdx.x;           // b*256 + n
    int b   = bn >> 8;
    int t   = threadIdx.x;
    int c   = t & 255;
    int sub = t >> 8;

    __shared__ int   xo0[14], xo1[14];   // x offsets premul by C_CH
    __shared__ float wxs[14];
    __shared__ int   yo0[14], yo1[14];   // y offsets premul by H*C_CH
    __shared__ float wys[14];
    __shared__ short otile[K1];          // [c*49 + s], 25088 B

    float yb = bbox[bn*4+0], xb = bbox[bn*4+1], hb = bbox[bn*4+2], wb = bbox[bn*4+3];
    int level = aid[bn] / 3;
    const short* gsrc = (level == 0) ? g0 : (level == 1) ? g1 : (level == 2) ? g2 : g3;
    int H = 128 >> level;
    float scale = 1.0f / (float)(4 << level);
    const short* gp = gsrc + (size_t)b * H * H * C_CH;

    if (t < 14) {
        float g  = ((float)t + 0.5f) * 0.5f;
        float l0 = (xb - 0.5f*wb) * scale - 0.5f;
        float bw = wb * scale * (1.0f/7.0f);
        float v  = fminf(fmaxf(l0 + bw * g, 0.0f), (float)(H-1));
        int i0 = (int)v;
        xo0[t] = i0 * C_CH;
        xo1[t] = min(i0 + 1, H - 1) * C_CH;
        wxs[t] = v - (float)i0;
    } else if (t < 28) {
        int sy = t - 14;
        float g  = ((float)sy + 0.5f) * 0.5f;
        float t0 = (yb - 0.5f*hb) * scale - 0.5f;
        float bh = hb * scale * (1.0f/7.0f);
        float v  = fminf(fmaxf(t0 + bh * g, 0.0f), (float)(H-1));
        int i0 = (int)v;
        yo0[sy] = i0 * H * C_CH;
        yo1[sy] = min(i0 + 1, H - 1) * H * C_CH;
        wys[sy] = v - (float)i0;
    }
    __syncthreads();

    #pragma unroll 2
    for (int s = sub; s < 49; s += 2) {
        int py = s / 7, px = s - py * 7;
        float acc = 0.0f;
        #pragma unroll
        for (int i = 0; i < 2; i++) {
            int sy = 2 * py + i;
            int ry0 = yo0[sy], ry1 = yo1[sy];
            float wy = wys[sy];
            #pragma unroll
            for (int j = 0; j < 2; j++) {
                int sx = 2 * px + j;
                int cx0 = xo0[sx] + c, cx1 = xo1[sx] + c;
                float wx = wxs[sx];
                float v00 = bf2f(gp[ry0 + cx0]);
                float v01 = bf2f(gp[ry0 + cx1]);
                float v10 = bf2f(gp[ry1 + cx0]);
                float v11 = bf2f(gp[ry1 + cx1]);
                float top = v00 * (1.0f - wx) + v01 * wx;
                float bot = v10 * (1.0f - wx) + v11 * wx;
                acc += top * (1.0f - wy) + bot * wy;
            }
        }
        otile[c * 49 + s] = (short)f2bf(acc * 0.25f);
    }
    __syncthreads();

    const i32x4* srcv = (const i32x4*)otile;
    i32x4* dstv = (i32x4*)(pooled + (size_t)bn * K1);
    for (int j = t; j < (K1 * 2) / 16; j += 512)   // 1568 chunks of 16B
        dstv[j] = srcv[j];
}

// ---------------- bf16 GEMM, 128x128 tile, double-buffered global_load_lds (R7-proven) ----------
// A:[512][K] bf16, Bt:[1024][K] bf16 (K-contiguous), part:[z][512][1024] f32
// flat grid = 4 * NP, NP = 8*z; decode keeps same-B-panel blocks on one XCD (id ≡ p mod 8).
__global__ __launch_bounds__(256) void gemm_db(
    const short* __restrict__ A, const short* __restrict__ Bt,
    float* __restrict__ part, int K, int KC, int NP)
{
    __shared__ short As[2][4096];    // [buf][128 rows * 32 shorts]
    __shared__ short Bs[2][4096];
    int t = threadIdx.x, lane = t & 63, w = t >> 6;
    int bid = blockIdx.x;
    int p = bid % NP, m = bid / NP;
    int n = p & 7, z = p >> 3;
    int m0 = m * 128, n0 = n * 128;
    size_t k0 = (size_t)z * KC;

    // staging: wave w fills chunks {2w, 2w+1} of each matrix per step.
    int gslot = (lane & 3) * 8;           // shorts
    int lrow  = lane >> 2;
    int qa0 = 2 * w, qa1 = 2 * w + 1;
    const short* gA0 = A  + (size_t)(m0 + qa0 * 16 + lrow) * K + k0 + gslot;
    const short* gA1 = A  + (size_t)(m0 + qa1 * 16 + lrow) * K + k0 + gslot;
    const short* gB0 = Bt + (size_t)(n0 + qa0 * 16 + lrow) * K + k0 + gslot;
    const short* gB1 = Bt + (size_t)(n0 + qa1 * 16 + lrow) * K + k0 + gslot;
    const short* lA0 = &As[0][qa0 * 512];
    const short* lA1 = &As[0][qa1 * 512];
    const short* lB0 = &Bs[0][qa0 * 512];
    const short* lB1 = &Bs[0][qa1 * 512];

    // fragment reads: wave quadrant (wr,wc), 4x4 16x16 subtiles
    int wr = (w >> 1) * 64, wc = (w & 1) * 64;
    int fr = lane & 15, kg = lane >> 4;
    int raoff = (wr + fr) * 32 + kg * 8;
    int rboff = (wc + fr) * 32 + kg * 8;

    int nsteps = KC >> 5;

    // prologue: stage buf 0
    stage16(gA0, lA0); stage16(gA1, lA1);
    stage16(gB0, lB0); stage16(gB1, lB1);
    __syncthreads();                      // drains vmcnt(0) before barrier

    f32x4 acc[4][4] = {};
    for (int s = 0; s < nsteps; ++s) {
        int cur = s & 1;
        if (s + 1 < nsteps) {             // issue next-tile loads BEFORE compute
            int nxt = cur ^ 1;
            int ks = (s + 1) * 32;
            stage16(gA0 + ks, lA0 + nxt * 4096);
            stage16(gA1 + ks, lA1 + nxt * 4096);
            stage16(gB0 + ks, lB0 + nxt * 4096);
            stage16(gB1 + ks, lB1 + nxt * 4096);
        }
        const short* ra = &As[cur][raoff];
        const short* rb = &Bs[cur][rboff];
        bf16x8 af[4], bm[4];
        #pragma unroll
        for (int i = 0; i < 4; i++) af[i] = *(const bf16x8*)(ra + i * 512);
        #pragma unroll
        for (int j = 0; j < 4; j++) bm[j] = *(const bf16x8*)(rb + j * 512);
        #pragma unroll
        for (int i = 0; i < 4; i++)
            #pragma unroll
            for (int j = 0; j < 4; j++)
                acc[i][j] = __builtin_amdgcn_mfma_f32_16x16x32_bf16(af[i], bm[j], acc[i][j], 0, 0, 0);
        __syncthreads();                  // one barrier/step; drains staging for next iter
    }

    float* base = part + (size_t)z * NBOX * FCDIM;
    #pragma unroll
    for (int i = 0; i < 4; i++)
        #pragma unroll
        for (int j = 0; j < 4; j++)
            #pragma unroll
            for (int r = 0; r < 4; r++) {
                int row = m0 + wr + i * 16 + kg * 4 + r;
                int col = n0 + wc + j * 16 + fr;
                base[(size_t)row * FCDIM + col] = acc[i][j][r];
            }
}

// ---------------- BN stage 1: sum split-K partials, per-block column stats ----------------
template<int NZ>
__global__ __launch_bounds__(256) void bn_stats1(
    const float* __restrict__ part, float* __restrict__ xsum, float* __restrict__ pstat)
{
    int tc = threadIdx.x & 63;
    int tr = threadIdx.x >> 6;
    int c  = blockIdx.x * 64 + tc;
    int r0 = blockIdx.y * 32;
    const size_t P = (size_t)NBOX * FCDIM;

    float s = 0.0f, q = 0.0f;
    #pragma unroll
    for (int rr = 0; rr < 8; rr++) {
        size_t o = (size_t)(r0 + tr + rr * 4) * FCDIM + c;
        float x = 0.0f;
        #pragma unroll
        for (int z = 0; z < NZ; z++) x += part[o + (size_t)z * P];
        xsum[o] = x;
        s += x; q += x * x;
    }
    __shared__ float Ss[4][64], Sq[4][64];
    Ss[tr][tc] = s; Sq[tr][tc] = q;
    __syncthreads();
    if (tr == 0) {
        float S = Ss[0][tc] + Ss[1][tc] + Ss[2][tc] + Ss[3][tc];
        float Q = Sq[0][tc] + Sq[1][tc] + Sq[2][tc] + Sq[3][tc];
        pstat[blockIdx.y * FCDIM + c] = S;
        pstat[16 * FCDIM + blockIdx.y * FCDIM + c] = Q;
    }
}

// ---------------- BN stage 2: finalize per-column scale/shift ----------------
__global__ __launch_bounds__(256) void bn_stats2(
    const float* __restrict__ pstat, const float* __restrict__ g,
    const float* __restrict__ be, float* __restrict__ scsh)
{
    int c = blockIdx.x * 256 + threadIdx.x;   // grid 4
    float S = 0.0f, Q = 0.0f;
    #pragma unroll
    for (int i = 0; i < 16; i++) {
        S += pstat[i * FCDIM + c];
        Q += pstat[16 * FCDIM + i * FCDIM + c];
    }
    float mu  = S * (1.0f / NBOX);
    float var = Q * (1.0f / NBOX) - mu * mu;
    float a = g[c] * rsqrtf(var + 1e-5f);
    scsh[c]         = a;
    scsh[FCDIM + c] = be[c] - mu * a;
}

// ---------------- BN apply (BN1): normalize + ReLU -> bf16 ----------------
__global__ __launch_bounds__(256) void bn_apply_bf(
    const float* __restrict__ xsum, const float* __restrict__ scsh,
    short* __restrict__ obf)
{
    size_t base = ((size_t)blockIdx.x * 256 + threadIdx.x) * 8;   // grid 256
    int c0 = (int)(base & (FCDIM - 1));
    float4 x0 = *(const float4*)(xsum + base);
    float4 x1 = *(const float4*)(xsum + base + 4);
    float4 a0 = *(const float4*)(scsh + c0);
    float4 a1 = *(const float4*)(scsh + c0 + 4);
    float4 b0 = *(const float4*)(scsh + FCDIM + c0);
    float4 b1 = *(const float4*)(scsh + FCDIM + c0 + 4);
    float r[8];
    r[0] = fmaxf(x0.x*a0.x + b0.x, 0.0f);
    r[1] = fmaxf(x0.y*a0.y + b0.y, 0.0f);
    r[2] = fmaxf(x0.z*a0.z + b0.z, 0.0f);
    r[3] = fmaxf(x0.w*a0.w + b0.w, 0.0f);
    r[4] = fmaxf(x1.x*a1.x + b1.x, 0.0f);
    r[5] = fmaxf(x1.y*a1.y + b1.y, 0.0f);
    r[6] = fmaxf(x1.z*a1.z + b1.z, 0.0f);
    r[7] = fmaxf(x1.w*a1.w + b1.w, 0.0f);
    union { unsigned short s[8]; i32x4 v; } u;
    #pragma unroll
    for (int i = 0; i < 8; i++) u.s[i] = f2bf(r[i]);
    *(i32x4*)(obf + base) = u.v;
}

// ---------------- fused BN2-apply + pred GEMV + bbox decode (consumes precomputed scsh) --------
__global__ __launch_bounds__(128) void bn2_pred_kernel(
    const float* __restrict__ xsum, const float* __restrict__ scsh,
    const float* __restrict__ pw, const float* __restrict__ pb,
    const float* __restrict__ bbox, const int* __restrict__ aid,
    const float* __restrict__ zp, float* __restrict__ out)
{
    int bn = blockIdx.x;
    int t  = threadIdx.x;
    __shared__ float xs[FCDIM];
    __shared__ float pr[OUTC];
    for (int i = t; i < FCDIM; i += 128)
        xs[i] = fmaxf(xsum[(size_t)bn * FCDIM + i] * scsh[i] + scsh[FCDIM + i], 0.0f);
    __syncthreads();

    float z = zp[bn];
    if (t < OUTC) {
        const float* wrow = pw + (size_t)t * FCDIM;
        float a = 0.0f;
        for (int k = 0; k < FCDIM; k += 4) {
            float4 w4 = *(const float4*)(wrow + k);
            a += xs[k] * w4.x + xs[k+1] * w4.y + xs[k+2] * w4.z + xs[k+3] * w4.w;
        }
        pr[t] = (a + pb[t]) * z;
    }
    __syncthreads();

    if (t < OUTC) {
        float y = bbox[bn*4+0], x = bbox[bn*4+1], h = bbox[bn*4+2], w = bbox[bn*4+3];
        int lvl = aid[bn] / 3;
        float st = 4.0f * exp2f((float)lvl * z);
        float o;
        if (t < 24) {
            int k = t / 6, j = t - k * 6;
            const float* d = &pr[5 + k * 6];
            switch (j) {
                case 0:  o = y + d[0] * h;  break;
                case 1:  o = x + d[1] * w;  break;
                case 2:  o = d[4] * st;     break;
                case 3:  o = h * expf(d[2]); break;
                case 4:  o = w * expf(d[3]); break;
                default: o = expf(d[5]) * st; break;
            }
        } else if (t < 29) {
            float m = pr[0];
            #pragma unroll
            for (int i = 1; i < 5; i++) m = fmaxf(m, pr[i]);
            float den = 0.0f;
            #pragma unroll
            for (int i = 0; i < 5; i++) den += expf(pr[i] - m);
            o = expf(pr[t - 24] - m) / den;
        } else if (t < 61) {
            int i = t - 29, k = i >> 3;
            const float* qq = &pr[29 + k * 8];
            float m = qq[0];
            #pragma unroll
            for (int ii = 1; ii < 8; ii++) m = fmaxf(m, qq[ii]);
            float den = 0.0f;
            #pragma unroll
            for (int ii = 0; ii < 8; ii++) den += expf(qq[ii] - m);
            o = expf(pr[t] - m) / den;
        } else {
            o = 1.0f / (1.0f + expf(-pr[t])) * 0.6f - 0.3f;
        }
        out[(size_t)bn * OUTC + t] = o;
    }
}

extern "C" void kernel_launch(void* const* d_in, const int* in_sizes, int n_in,
                              void* d_out, int out_size, void* d_ws, size_t ws_size,
                              hipStream_t stream)
{
    const float* f0   = (const float*)d_in[0];
    const float* f1   = (const float*)d_in[1];
    const float* f2   = (const float*)d_in[2];
    const float* f3   = (const float*)d_in[3];
    const float* bbox = (const float*)d_in[4];
    const int*   aid  = (const int*)d_in[5];
    const float* zp   = (const float*)d_in[6];
    const float* fc1w = (const float*)d_in[7];
    const float* bn1g = (const float*)d_in[9];
    const float* bn1b = (const float*)d_in[10];
    const float* fc2w = (const float*)d_in[11];
    const float* bn2g = (const float*)d_in[13];
    const float* bn2b = (const float*)d_in[14];
    const float* pw   = (const float*)d_in[15];
    const float* pb   = (const float*)d_in[16];
    float* out = (float*)d_out;

    // workspace layout (linear, ~145.4 MB of the 256 MiB ws)
    char* ws = (char*)d_ws;
    short* pooled = (short*)(ws);                    // 12,845,056
    short* gt0    = (short*)(ws + 13631488);         // 16,777,216
    short* gt1    = (short*)(ws + 30408704);         //  4,194,304
    short* gt2    = (short*)(ws + 34603008);         //  1,048,576
    short* gt3    = (short*)(ws + 35651584);         //    262,144
    short* w1     = (short*)(ws + 36700160);         // 25,690,112
    short* w2     = (short*)(ws + 62390272);         //  2,097,152
    float* part1  = (float*)(ws + 64487424);         // Z1 * 2,097,152 = 29,360,128
    float* part2  = (float*)(ws + 123207680);        // Z2 * 2,097,152 = 16,777,216
    float* xsum   = (float*)(ws + 139984896);        //  2,097,152
    short* x1n    = (short*)(ws + 142082048);        //  1,048,576
    float* pstat  = (float*)(ws + 145227776);        //    131,072
    float* scsh   = (float*)(ws + 145358848);        //      8,192

    // 1 merged streaming launch: transpose (1360) + w1 cast (1568) + w2 cast (128)
    stream_prep_kernel<<<1360 + 1568 + 128, 256, 0, stream>>>(
        f0, f1, f2, f3, gt0, gt1, gt2, gt3, fc1w, w1, fc2w, w2);

    roi_kernel<<<NBOX, 512, 0, stream>>>(gt0, gt1, gt2, gt3, bbox, aid, pooled);

    gemm_db<<<4 * 8 * Z1, 256, 0, stream>>>(pooled, w1, part1, K1, K1 / Z1, 8 * Z1);

    bn_stats1<Z1><<<dim3(16, 16), 256, 0, stream>>>(part1, xsum, pstat);
    bn_stats2<<<4, 256, 0, stream>>>(pstat, bn1g, bn1b, scsh);
    bn_apply_bf<<<256, 256, 0, stream>>>(xsum, scsh, x1n);

    gemm_db<<<4 * 8 * Z2, 256, 0, stream>>>(x1n, w2, part2, FCDIM, FCDIM / Z2, 8 * Z2);

    bn_stats1<Z2><<<dim3(16, 16), 256, 0, stream>>>(part2, xsum, pstat);
    bn_stats2<<<4, 256, 0, stream>>>(pstat, bn2g, bn2b, scsh);

    bn2_pred_kernel<<<NBOX, 128, 0, stream>>>(xsum, scsh, pw, pb, bbox, aid, zp, out);
}

// Round 18
// 133.445 us; speedup vs baseline: 1.0835x; 1.0133x over previous
//
#include <hip/hip_runtime.h>
#include <cstdint>
#include <cstddef>

typedef __attribute__((ext_vector_type(8))) short bf16x8;
typedef __attribute__((ext_vector_type(4))) float f32x4;
typedef __attribute__((ext_vector_type(4))) int   i32x4;

#define C_CH   256
#define NBOX   512      // B*N
#define FCDIM  1024
#define K1     12544    // C*7*7
#define OUTC   93
#define Z1     14       // split-K for FC1 (KC = 896, 28 steps)
#define Z2     8        // split-K for FC2 (KC = 128, 4 steps)

__device__ __forceinline__ unsigned short f2bf(float f) {
    unsigned u = __float_as_uint(f);
    u += 0x7fffu + ((u >> 16) & 1u);      // RNE
    return (unsigned short)(u >> 16);
}
__device__ __forceinline__ float bf2f(short s) {
    return __uint_as_float((unsigned)(unsigned short)s << 16);
}
__device__ __forceinline__ void stage16(const void* g, const void* l) {
    __builtin_amdgcn_global_load_lds(
        (const __attribute__((address_space(1))) void*)g,
        (__attribute__((address_space(3))) void*)l, 16, 0, 0);
}

// ---------------- merged streaming: feature transpose (blocks 0..1359) + weight casts ----------
// R18: transpose write path coalesced — LDS pitch 68 (8B-aligned rows, 2-way banks) and the
// global store loop emits 8B per lane (16 lanes = 128B row segment, wave = 4 rows, 8 iters)
// instead of 16 iters of 4B stores. Read phase and cast path identical to R15.
__global__ __launch_bounds__(256) void stream_prep_kernel(
    const float* __restrict__ f0, const float* __restrict__ f1,
    const float* __restrict__ f2, const float* __restrict__ f3,
    short* __restrict__ g0, short* __restrict__ g1,
    short* __restrict__ g2, short* __restrict__ g3,
    const float* __restrict__ w1f, short* __restrict__ w1b,
    const float* __restrict__ w2f, short* __restrict__ w2b)
{
    __shared__ short tile[128 * 68];
    int id = blockIdx.x;
    int t  = threadIdx.x;

    if (id >= 1360) {                      // ---- streaming cast path (R15-proven) ----
        int cb = id - 1360;
        const float* src; short* dst;
        if (cb < 6272) { src = w1f; dst = w1b; }
        else           { src = w2f; dst = w2b; cb -= 6272; }
        size_t i = ((size_t)cb * 256 + t) * 8;
        const float4* p = (const float4*)(src + i);
        float4 a = p[0], b = p[1];
        union { unsigned short s[8]; i32x4 v; } u;
        u.s[0] = f2bf(a.x); u.s[1] = f2bf(a.y); u.s[2] = f2bf(a.z); u.s[3] = f2bf(a.w);
        u.s[4] = f2bf(b.x); u.s[5] = f2bf(b.y); u.s[6] = f2bf(b.z); u.s[7] = f2bf(b.w);
        *(i32x4*)(dst + i) = u.v;
        return;
    }

    const float* src; short* dst; int HW, nx;
    if (id < 1024)      { src = f0; dst = g0; HW = 16384; nx = 128; }
    else if (id < 1280) { id -= 1024; src = f1; dst = g1; HW = 4096; nx = 32; }
    else if (id < 1344) { id -= 1280; src = f2; dst = g2; HW = 1024; nx = 8; }
    else                { id -= 1344; src = f3; dst = g3; HW = 256;  nx = 2; }
    int xb = id % nx;  int rest = id / nx;
    int cy = rest & 3; int b = rest >> 2;
    int p0 = xb * 128, c0 = cy * 64;

    const float* s = src + ((size_t)b * C_CH + c0) * HW + p0;
    #pragma unroll
    for (int it = 0; it < 16; ++it) {
        int slot = it * 256 + t;           // over [64 ch][64 pixel-pairs]
        int cl = slot >> 6;
        int pp = slot & 63;
        float2 v = *(const float2*)(s + (size_t)cl * HW + pp * 2);
        tile[(pp * 2) * 68 + cl]     = (short)f2bf(v.x);
        tile[(pp * 2 + 1) * 68 + cl] = (short)f2bf(v.y);
    }
    __syncthreads();
    short* d = dst + ((size_t)b * HW + p0) * C_CH + c0;
    #pragma unroll
    for (int it = 0; it < 8; ++it) {
        int pl = it * 16 + (t >> 4);       // 0..127 (4 rows per wave)
        int c4 = (t & 15) * 4;             // 4 channels / lane, 8B store
        *(unsigned long long*)(d + (size_t)pl * C_CH + c4) =
            *(const unsigned long long*)&tile[pl * 68 + c4];
    }
}

// ---------------- ROI align: channel-last bf16 features, one block per box ----------------
__global__ __launch_bounds__(512) void roi_kernel(
    const short* __restrict__ g0, const short* __restrict__ g1,
    const short* __restrict__ g2, const short* __restrict__ g3,
    const float* __restrict__ bbox, const int* __restrict__ aid,
    short* __restrict__ pooled)
{
    int bn  = blockIdx.x;           // b*256 + n
    int b   = bn >> 8;
    int t   = threadIdx.x;
    int c   = t & 255;
    int sub = t >> 8;

    __shared__ int   xo0[14], xo1[14];   // x offsets premul by C_CH
    __shared__ float wxs[14];
    __shared__ int   yo0[14], yo1[14];   // y offsets premul by H*C_CH
    __shared__ float wys[14];
    __shared__ short otile[K1];          // [c*49 + s], 25088 B

    float yb = bbox[bn*4+0], xb = bbox[bn*4+1], hb = bbox[bn*4+2], wb = bbox[bn*4+3];
    int level = aid[bn] / 3;
    const short* gsrc = (level == 0) ? g0 : (level == 1) ? g1 : (level == 2) ? g2 : g3;
    int H = 128 >> level;
    float scale = 1.0f / (float)(4 << level);
    const short* gp = gsrc + (size_t)b * H * H * C_CH;

    if (t < 14) {
        float g  = ((float)t + 0.5f) * 0.5f;
        float l0 = (xb - 0.5f*wb) * scale - 0.5f;
        float bw = wb * scale * (1.0f/7.0f);
        float v  = fminf(fmaxf(l0 + bw * g, 0.0f), (float)(H-1));
        int i0 = (int)v;
        xo0[t] = i0 * C_CH;
        xo1[t] = min(i0 + 1, H - 1) * C_CH;
        wxs[t] = v - (float)i0;
    } else if (t < 28) {
        int sy = t - 14;
        float g  = ((float)sy + 0.5f) * 0.5f;
        float t0 = (yb - 0.5f*hb) * scale - 0.5f;
        float bh = hb * scale * (1.0f/7.0f);
        float v  = fminf(fmaxf(t0 + bh * g, 0.0f), (float)(H-1));
        int i0 = (int)v;
        yo0[sy] = i0 * H * C_CH;
        yo1[sy] = min(i0 + 1, H - 1) * H * C_CH;
        wys[sy] = v - (float)i0;
    }
    __syncthreads();

    #pragma unroll 2
    for (int s = sub; s < 49; s += 2) {
        int py = s / 7, px = s - py * 7;
        float acc = 0.0f;
        #pragma unroll
        for (int i = 0; i < 2; i++) {
            int sy = 2 * py + i;
            int ry0 = yo0[sy], ry1 = yo1[sy];
            float wy = wys[sy];
            #pragma unroll
            for (int j = 0; j < 2; j++) {
                int sx = 2 * px + j;
                int cx0 = xo0[sx] + c, cx1 = xo1[sx] + c;
                float wx = wxs[sx];
                float v00 = bf2f(gp[ry0 + cx0]);
                float v01 = bf2f(gp[ry0 + cx1]);
                float v10 = bf2f(gp[ry1 + cx0]);
                float v11 = bf2f(gp[ry1 + cx1]);
                float top = v00 * (1.0f - wx) + v01 * wx;
                float bot = v10 * (1.0f - wx) + v11 * wx;
                acc += top * (1.0f - wy) + bot * wy;
            }
        }
        otile[c * 49 + s] = (short)f2bf(acc * 0.25f);
    }
    __syncthreads();

    const i32x4* srcv = (const i32x4*)otile;
    i32x4* dstv = (i32x4*)(pooled + (size_t)bn * K1);
    for (int j = t; j < (K1 * 2) / 16; j += 512)   // 1568 chunks of 16B
        dstv[j] = srcv[j];
}

// ---------------- bf16 GEMM, 128x128 tile, double-buffered global_load_lds (R7-proven) ----------
// A:[512][K] bf16, Bt:[1024][K] bf16 (K-contiguous), part:[z][512][1024] f32
// flat grid = 4 * NP, NP = 8*z; decode keeps same-B-panel blocks on one XCD (id ≡ p mod 8).
__global__ __launch_bounds__(256) void gemm_db(
    const short* __restrict__ A, const short* __restrict__ Bt,
    float* __restrict__ part, int K, int KC, int NP)
{
    __shared__ short As[2][4096];    // [buf][128 rows * 32 shorts]
    __shared__ short Bs[2][4096];
    int t = threadIdx.x, lane = t & 63, w = t >> 6;
    int bid = blockIdx.x;
    int p = bid % NP, m = bid / NP;
    int n = p & 7, z = p >> 3;
    int m0 = m * 128, n0 = n * 128;
    size_t k0 = (size_t)z * KC;

    // staging: wave w fills chunks {2w, 2w+1} of each matrix per step.
    int gslot = (lane & 3) * 8;           // shorts
    int lrow  = lane >> 2;
    int qa0 = 2 * w, qa1 = 2 * w + 1;
    const short* gA0 = A  + (size_t)(m0 + qa0 * 16 + lrow) * K + k0 + gslot;
    const short* gA1 = A  + (size_t)(m0 + qa1 * 16 + lrow) * K + k0 + gslot;
    const short* gB0 = Bt + (size_t)(n0 + qa0 * 16 + lrow) * K + k0 + gslot;
    const short* gB1 = Bt + (size_t)(n0 + qa1 * 16 + lrow) * K + k0 + gslot;
    const short* lA0 = &As[0][qa0 * 512];
    const short* lA1 = &As[0][qa1 * 512];
    const short* lB0 = &Bs[0][qa0 * 512];
    const short* lB1 = &Bs[0][qa1 * 512];

    // fragment reads: wave quadrant (wr,wc), 4x4 16x16 subtiles
    int wr = (w >> 1) * 64, wc = (w & 1) * 64;
    int fr = lane & 15, kg = lane >> 4;
    int raoff = (wr + fr) * 32 + kg * 8;
    int rboff = (wc + fr) * 32 + kg * 8;

    int nsteps = KC >> 5;

    // prologue: stage buf 0
    stage16(gA0, lA0); stage16(gA1, lA1);
    stage16(gB0, lB0); stage16(gB1, lB1);
    __syncthreads();                      // drains vmcnt(0) before barrier

    f32x4 acc[4][4] = {};
    for (int s = 0; s < nsteps; ++s) {
        int cur = s & 1;
        if (s + 1 < nsteps) {             // issue next-tile loads BEFORE compute
            int nxt = cur ^ 1;
            int ks = (s + 1) * 32;
            stage16(gA0 + ks, lA0 + nxt * 4096);
            stage16(gA1 + ks, lA1 + nxt * 4096);
            stage16(gB0 + ks, lB0 + nxt * 4096);
            stage16(gB1 + ks, lB1 + nxt * 4096);
        }
        const short* ra = &As[cur][raoff];
        const short* rb = &Bs[cur][rboff];
        bf16x8 af[4], bm[4];
        #pragma unroll
        for (int i = 0; i < 4; i++) af[i] = *(const bf16x8*)(ra + i * 512);
        #pragma unroll
        for (int j = 0; j < 4; j++) bm[j] = *(const bf16x8*)(rb + j * 512);
        #pragma unroll
        for (int i = 0; i < 4; i++)
            #pragma unroll
            for (int j = 0; j < 4; j++)
                acc[i][j] = __builtin_amdgcn_mfma_f32_16x16x32_bf16(af[i], bm[j], acc[i][j], 0, 0, 0);
        __syncthreads();                  // one barrier/step; drains staging for next iter
    }

    float* base = part + (size_t)z * NBOX * FCDIM;
    #pragma unroll
    for (int i = 0; i < 4; i++)
        #pragma unroll
        for (int j = 0; j < 4; j++)
            #pragma unroll
            for (int r = 0; r < 4; r++) {
                int row = m0 + wr + i * 16 + kg * 4 + r;
                int col = n0 + wc + j * 16 + fr;
                base[(size_t)row * FCDIM + col] = acc[i][j][r];
            }
}

// ---------------- BN stage 1: sum split-K partials, per-block column stats ----------------
template<int NZ>
__global__ __launch_bounds__(256) void bn_stats1(
    const float* __restrict__ part, float* __restrict__ xsum, float* __restrict__ pstat)
{
    int tc = threadIdx.x & 63;
    int tr = threadIdx.x >> 6;
    int c  = blockIdx.x * 64 + tc;
    int r0 = blockIdx.y * 32;
    const size_t P = (size_t)NBOX * FCDIM;

    float s = 0.0f, q = 0.0f;
    #pragma unroll
    for (int rr = 0; rr < 8; rr++) {
        size_t o = (size_t)(r0 + tr + rr * 4) * FCDIM + c;
        float x = 0.0f;
        #pragma unroll
        for (int z = 0; z < NZ; z++) x += part[o + (size_t)z * P];
        xsum[o] = x;
        s += x; q += x * x;
    }
    __shared__ float Ss[4][64], Sq[4][64];
    Ss[tr][tc] = s; Sq[tr][tc] = q;
    __syncthreads();
    if (tr == 0) {
        float S = Ss[0][tc] + Ss[1][tc] + Ss[2][tc] + Ss[3][tc];
        float Q = Sq[0][tc] + Sq[1][tc] + Sq[2][tc] + Sq[3][tc];
        pstat[blockIdx.y * FCDIM + c] = S;
        pstat[16 * FCDIM + blockIdx.y * FCDIM + c] = Q;
    }
}

// ---------------- BN stage 2: finalize per-column scale/shift ----------------
__global__ __launch_bounds__(256) void bn_stats2(
    const float* __restrict__ pstat, const float* __restrict__ g,
    const float* __restrict__ be, float* __restrict__ scsh)
{
    int c = blockIdx.x * 256 + threadIdx.x;   // grid 4
    float S = 0.0f, Q = 0.0f;
    #pragma unroll
    for (int i = 0; i < 16; i++) {
        S += pstat[i * FCDIM + c];
        Q += pstat[16 * FCDIM + i * FCDIM + c];
    }
    float mu  = S * (1.0f / NBOX);
    float var = Q * (1.0f / NBOX) - mu * mu;
    float a = g[c] * rsqrtf(var + 1e-5f);
    scsh[c]         = a;
    scsh[FCDIM + c] = be[c] - mu * a;
}

// ---------------- BN apply (BN1): normalize + ReLU -> bf16 ----------------
__global__ __launch_bounds__(256) void bn_apply_bf(
    const float* __restrict__ xsum, const float* __restrict__ scsh,
    short* __restrict__ obf)
{
    size_t base = ((size_t)blockIdx.x * 256 + threadIdx.x) * 8;   // grid 256
    int c0 = (int)(base & (FCDIM - 1));
    float4 x0 = *(const float4*)(xsum + base);
    float4 x1 = *(const float4*)(xsum + base + 4);
    float4 a0 = *(const float4*)(scsh + c0);
    float4 a1 = *(const float4*)(scsh + c0 + 4);
    float4 b0 = *(const float4*)(scsh + FCDIM + c0);
    float4 b1 = *(const float4*)(scsh + FCDIM + c0 + 4);
    float r[8];
    r[0] = fmaxf(x0.x*a0.x + b0.x, 0.0f);
    r[1] = fmaxf(x0.y*a0.y + b0.y, 0.0f);
    r[2] = fmaxf(x0.z*a0.z + b0.z, 0.0f);
    r[3] = fmaxf(x0.w*a0.w + b0.w, 0.0f);
    r[4] = fmaxf(x1.x*a1.x + b1.x, 0.0f);
    r[5] = fmaxf(x1.y*a1.y + b1.y, 0.0f);
    r[6] = fmaxf(x1.z*a1.z + b1.z, 0.0f);
    r[7] = fmaxf(x1.w*a1.w + b1.w, 0.0f);
    union { unsigned short s[8]; i32x4 v; } u;
    #pragma unroll
    for (int i = 0; i < 8; i++) u.s[i] = f2bf(r[i]);
    *(i32x4*)(obf + base) = u.v;
}

// ---------------- fused BN2-apply + pred GEMV + bbox decode (consumes precomputed scsh) --------
__global__ __launch_bounds__(128) void bn2_pred_kernel(
    const float* __restrict__ xsum, const float* __restrict__ scsh,
    const float* __restrict__ pw, const float* __restrict__ pb,
    const float* __restrict__ bbox, const int* __restrict__ aid,
    const float* __restrict__ zp, float* __restrict__ out)
{
    int bn = blockIdx.x;
    int t  = threadIdx.x;
    __shared__ float xs[FCDIM];
    __shared__ float pr[OUTC];
    for (int i = t; i < FCDIM; i += 128)
        xs[i] = fmaxf(xsum[(size_t)bn * FCDIM + i] * scsh[i] + scsh[FCDIM + i], 0.0f);
    __syncthreads();

    float z = zp[bn];
    if (t < OUTC) {
        const float* wrow = pw + (size_t)t * FCDIM;
        float a = 0.0f;
        for (int k = 0; k < FCDIM; k += 4) {
            float4 w4 = *(const float4*)(wrow + k);
            a += xs[k] * w4.x + xs[k+1] * w4.y + xs[k+2] * w4.z + xs[k+3] * w4.w;
        }
        pr[t] = (a + pb[t]) * z;
    }
    __syncthreads();

    if (t < OUTC) {
        float y = bbox[bn*4+0], x = bbox[bn*4+1], h = bbox[bn*4+2], w = bbox[bn*4+3];
        int lvl = aid[bn] / 3;
        float st = 4.0f * exp2f((float)lvl * z);
        float o;
        if (t < 24) {
            int k = t / 6, j = t - k * 6;
            const float* d = &pr[5 + k * 6];
            switch (j) {
                case 0:  o = y + d[0] * h;  break;
                case 1:  o = x + d[1] * w;  break;
                case 2:  o = d[4] * st;     break;
                case 3:  o = h * expf(d[2]); break;
                case 4:  o = w * expf(d[3]); break;
                default: o = expf(d[5]) * st; break;
            }
        } else if (t < 29) {
            float m = pr[0];
            #pragma unroll
            for (int i = 1; i < 5; i++) m = fmaxf(m, pr[i]);
            float den = 0.0f;
            #pragma unroll
            for (int i = 0; i < 5; i++) den += expf(pr[i] - m);
            o = expf(pr[t - 24] - m) / den;
        } else if (t < 61) {
            int i = t - 29, k = i >> 3;
            const float* qq = &pr[29 + k * 8];
            float m = qq[0];
            #pragma unroll
            for (int ii = 1; ii < 8; ii++) m = fmaxf(m, qq[ii]);
            float den = 0.0f;
            #pragma unroll
            for (int ii = 0; ii < 8; ii++) den += expf(qq[ii] - m);
            o = expf(pr[t] - m) / den;
        } else {
            o = 1.0f / (1.0f + expf(-pr[t])) * 0.6f - 0.3f;
        }
        out[(size_t)bn * OUTC + t] = o;
    }
}

extern "C" void kernel_launch(void* const* d_in, const int* in_sizes, int n_in,
                              void* d_out, int out_size, void* d_ws, size_t ws_size,
                              hipStream_t stream)
{
    const float* f0   = (const float*)d_in[0];
    const float* f1   = (const float*)d_in[1];
    const float* f2   = (const float*)d_in[2];
    const float* f3   = (const float*)d_in[3];
    const float* bbox = (const float*)d_in[4];
    const int*   aid  = (const int*)d_in[5];
    const float* zp   = (const float*)d_in[6];
    const float* fc1w = (const float*)d_in[7];
    const float* bn1g = (const float*)d_in[9];
    const float* bn1b = (const float*)d_in[10];
    const float* fc2w = (const float*)d_in[11];
    const float* bn2g = (const float*)d_in[13];
    const float* bn2b = (const float*)d_in[14];
    const float* pw   = (const float*)d_in[15];
    const float* pb   = (const float*)d_in[16];
    float* out = (float*)d_out;

    // workspace layout (linear, ~145.4 MB of the 256 MiB ws)
    char* ws = (char*)d_ws;
    short* pooled = (short*)(ws);                    // 12,845,056
    short* gt0    = (short*)(ws + 13631488);         // 16,777,216
    short* gt1    = (short*)(ws + 30408704);         //  4,194,304
    short* gt2    = (short*)(ws + 34603008);         //  1,048,576
    short* gt3    = (short*)(ws + 35651584);         //    262,144
    short* w1     = (short*)(ws + 36700160);         // 25,690,112
    short* w2     = (short*)(ws + 62390272);         //  2,097,152
    float* part1  = (float*)(ws + 64487424);         // Z1 * 2,097,152 = 29,360,128
    float* part2  = (float*)(ws + 123207680);        // Z2 * 2,097,152 = 16,777,216
    float* xsum   = (float*)(ws + 139984896);        //  2,097,152
    short* x1n    = (short*)(ws + 142082048);        //  1,048,576
    float* pstat  = (float*)(ws + 145227776);        //    131,072
    float* scsh   = (float*)(ws + 145358848);        //      8,192

    // 1 merged streaming launch: transpose (1360) + w1 cast (6272) + w2 cast (512)
    stream_prep_kernel<<<1360 + 6272 + 512, 256, 0, stream>>>(
        f0, f1, f2, f3, gt0, gt1, gt2, gt3, fc1w, w1, fc2w, w2);

    roi_kernel<<<NBOX, 512, 0, stream>>>(gt0, gt1, gt2, gt3, bbox, aid, pooled);

    gemm_db<<<4 * 8 * Z1, 256, 0, stream>>>(pooled, w1, part1, K1, K1 / Z1, 8 * Z1);

    bn_stats1<Z1><<<dim3(16, 16), 256, 0, stream>>>(part1, xsum, pstat);
    bn_stats2<<<4, 256, 0, stream>>>(pstat, bn1g, bn1b, scsh);
    bn_apply_bf<<<256, 256, 0, stream>>>(xsum, scsh, x1n);

    gemm_db<<<4 * 8 * Z2, 256, 0, stream>>>(x1n, w2, part2, FCDIM, FCDIM / Z2, 8 * Z2);

    bn_stats1<Z2><<<dim3(16, 16), 256, 0, stream>>>(part2, xsum, pstat);
    bn_stats2<<<4, 256, 0, stream>>>(pstat, bn2g, bn2b, scsh);

    bn2_pred_kernel<<<NBOX, 128, 0, stream>>>(xsum, scsh, pw, pb, bbox, aid, zp, out);
}

// Round 19
// 133.397 us; speedup vs baseline: 1.0839x; 1.0004x over previous
//
#include <hip/hip_runtime.h>
#include <cstdint>
#include <cstddef>

typedef __attribute__((ext_vector_type(8))) short bf16x8;
typedef __attribute__((ext_vector_type(4))) float f32x4;
typedef __attribute__((ext_vector_type(4))) int   i32x4;

#define C_CH   256
#define NBOX   512      // B*N
#define FCDIM  1024
#define K1     12544    // C*7*7
#define OUTC   93
#define Z1     14       // split-K for FC1 (KC = 896, 28 steps)
#define Z2     8        // split-K for FC2 (KC = 128, 4 steps)

__device__ __forceinline__ unsigned short f2bf(float f) {
    unsigned u = __float_as_uint(f);
    u += 0x7fffu + ((u >> 16) & 1u);      // RNE
    return (unsigned short)(u >> 16);
}
__device__ __forceinline__ float bf2f(short s) {
    return __uint_as_float((unsigned)(unsigned short)s << 16);
}
__device__ __forceinline__ void stage16(const void* g, const void* l) {
    __builtin_amdgcn_global_load_lds(
        (const __attribute__((address_space(1))) void*)g,
        (__attribute__((address_space(3))) void*)l, 16, 0, 0);
}

// ---------------- merged streaming: feature transpose (blocks 0..1359) + weight casts ----------
// R19: LDS pitch 66 (33-word odd stride -> conflict-free transpose WRITES; ~2-way reads)
// combined with the 8B global store loop (16 lanes = 128B row segment, wave = 4 rows).
__global__ __launch_bounds__(256) void stream_prep_kernel(
    const float* __restrict__ f0, const float* __restrict__ f1,
    const float* __restrict__ f2, const float* __restrict__ f3,
    short* __restrict__ g0, short* __restrict__ g1,
    short* __restrict__ g2, short* __restrict__ g3,
    const float* __restrict__ w1f, short* __restrict__ w1b,
    const float* __restrict__ w2f, short* __restrict__ w2b)
{
    __shared__ short tile[128 * 66];
    int id = blockIdx.x;
    int t  = threadIdx.x;

    if (id >= 1360) {                      // ---- streaming cast path (R15-proven) ----
        int cb = id - 1360;
        const float* src; short* dst;
        if (cb < 6272) { src = w1f; dst = w1b; }
        else           { src = w2f; dst = w2b; cb -= 6272; }
        size_t i = ((size_t)cb * 256 + t) * 8;
        const float4* p = (const float4*)(src + i);
        float4 a = p[0], b = p[1];
        union { unsigned short s[8]; i32x4 v; } u;
        u.s[0] = f2bf(a.x); u.s[1] = f2bf(a.y); u.s[2] = f2bf(a.z); u.s[3] = f2bf(a.w);
        u.s[4] = f2bf(b.x); u.s[5] = f2bf(b.y); u.s[6] = f2bf(b.z); u.s[7] = f2bf(b.w);
        *(i32x4*)(dst + i) = u.v;
        return;
    }

    const float* src; short* dst; int HW, nx;
    if (id < 1024)      { src = f0; dst = g0; HW = 16384; nx = 128; }
    else if (id < 1280) { id -= 1024; src = f1; dst = g1; HW = 4096; nx = 32; }
    else if (id < 1344) { id -= 1280; src = f2; dst = g2; HW = 1024; nx = 8; }
    else                { id -= 1344; src = f3; dst = g3; HW = 256;  nx = 2; }
    int xb = id % nx;  int rest = id / nx;
    int cy = rest & 3; int b = rest >> 2;
    int p0 = xb * 128, c0 = cy * 64;

    const float* s = src + ((size_t)b * C_CH + c0) * HW + p0;
    #pragma unroll
    for (int it = 0; it < 16; ++it) {
        int slot = it * 256 + t;           // over [64 ch][64 pixel-pairs]
        int cl = slot >> 6;
        int pp = slot & 63;
        float2 v = *(const float2*)(s + (size_t)cl * HW + pp * 2);
        tile[(pp * 2) * 66 + cl]     = (short)f2bf(v.x);
        tile[(pp * 2 + 1) * 66 + cl] = (short)f2bf(v.y);
    }
    __syncthreads();
    short* d = dst + ((size_t)b * HW + p0) * C_CH + c0;
    #pragma unroll
    for (int it = 0; it < 8; ++it) {
        int pl = it * 16 + (t >> 4);       // 0..127 (4 rows per wave)
        int c4 = (t & 15) * 4;             // 4 channels / lane, 8B store
        *(unsigned long long*)(d + (size_t)pl * C_CH + c4) =
            *(const unsigned long long*)&tile[pl * 66 + c4];
    }
}

// ---------------- ROI align: channel-last bf16 features, one block per box ----------------
__global__ __launch_bounds__(512) void roi_kernel(
    const short* __restrict__ g0, const short* __restrict__ g1,
    const short* __restrict__ g2, const short* __restrict__ g3,
    const float* __restrict__ bbox, const int* __restrict__ aid,
    short* __restrict__ pooled)
{
    int bn  = blockIdx.x;           // b*256 + n
    int b   = bn >> 8;
    int t   = threadIdx.x;
    int c   = t & 255;
    int sub = t >> 8;

    __shared__ int   xo0[14], xo1[14];   // x offsets premul by C_CH
    __shared__ float wxs[14];
    __shared__ int   yo0[14], yo1[14];   // y offsets premul by H*C_CH
    __shared__ float wys[14];
    __shared__ short otile[K1];          // [c*49 + s], 25088 B

    float yb = bbox[bn*4+0], xb = bbox[bn*4+1], hb = bbox[bn*4+2], wb = bbox[bn*4+3];
    int level = aid[bn] / 3;
    const short* gsrc = (level == 0) ? g0 : (level == 1) ? g1 : (level == 2) ? g2 : g3;
    int H = 128 >> level;
    float scale = 1.0f / (float)(4 << level);
    const short* gp = gsrc + (size_t)b * H * H * C_CH;

    if (t < 14) {
        float g  = ((float)t + 0.5f) * 0.5f;
        float l0 = (xb - 0.5f*wb) * scale - 0.5f;
        float bw = wb * scale * (1.0f/7.0f);
        float v  = fminf(fmaxf(l0 + bw * g, 0.0f), (float)(H-1));
        int i0 = (int)v;
        xo0[t] = i0 * C_CH;
        xo1[t] = min(i0 + 1, H - 1) * C_CH;
        wxs[t] = v - (float)i0;
    } else if (t < 28) {
        int sy = t - 14;
        float g  = ((float)sy + 0.5f) * 0.5f;
        float t0 = (yb - 0.5f*hb) * scale - 0.5f;
        float bh = hb * scale * (1.0f/7.0f);
        float v  = fminf(fmaxf(t0 + bh * g, 0.0f), (float)(H-1));
        int i0 = (int)v;
        yo0[sy] = i0 * H * C_CH;
        yo1[sy] = min(i0 + 1, H - 1) * H * C_CH;
        wys[sy] = v - (float)i0;
    }
    __syncthreads();

    #pragma unroll 2
    for (int s = sub; s < 49; s += 2) {
        int py = s / 7, px = s - py * 7;
        float acc = 0.0f;
        #pragma unroll
        for (int i = 0; i < 2; i++) {
            int sy = 2 * py + i;
            int ry0 = yo0[sy], ry1 = yo1[sy];
            float wy = wys[sy];
            #pragma unroll
            for (int j = 0; j < 2; j++) {
                int sx = 2 * px + j;
                int cx0 = xo0[sx] + c, cx1 = xo1[sx] + c;
                float wx = wxs[sx];
                float v00 = bf2f(gp[ry0 + cx0]);
                float v01 = bf2f(gp[ry0 + cx1]);
                float v10 = bf2f(gp[ry1 + cx0]);
                float v11 = bf2f(gp[ry1 + cx1]);
                float top = v00 * (1.0f - wx) + v01 * wx;
                float bot = v10 * (1.0f - wx) + v11 * wx;
                acc += top * (1.0f - wy) + bot * wy;
            }
        }
        otile[c * 49 + s] = (short)f2bf(acc * 0.25f);
    }
    __syncthreads();

    const i32x4* srcv = (const i32x4*)otile;
    i32x4* dstv = (i32x4*)(pooled + (size_t)bn * K1);
    for (int j = t; j < (K1 * 2) / 16; j += 512)   // 1568 chunks of 16B
        dstv[j] = srcv[j];
}

// ---------------- bf16 GEMM, 128x128 tile, double-buffered global_load_lds (R7-proven) ----------
// A:[512][K] bf16, Bt:[1024][K] bf16 (K-contiguous), part:[z][512][1024] f32
// flat grid = 4 * NP, NP = 8*z; decode keeps same-B-panel blocks on one XCD (id ≡ p mod 8).
__global__ __launch_bounds__(256) void gemm_db(
    const short* __restrict__ A, const short* __restrict__ Bt,
    float* __restrict__ part, int K, int KC, int NP)
{
    __shared__ short As[2][4096];    // [buf][128 rows * 32 shorts]
    __shared__ short Bs[2][4096];
    int t = threadIdx.x, lane = t & 63, w = t >> 6;
    int bid = blockIdx.x;
    int p = bid % NP, m = bid / NP;
    int n = p & 7, z = p >> 3;
    int m0 = m * 128, n0 = n * 128;
    size_t k0 = (size_t)z * KC;

    // staging: wave w fills chunks {2w, 2w+1} of each matrix per step.
    int gslot = (lane & 3) * 8;           // shorts
    int lrow  = lane >> 2;
    int qa0 = 2 * w, qa1 = 2 * w + 1;
    const short* gA0 = A  + (size_t)(m0 + qa0 * 16 + lrow) * K + k0 + gslot;
    const short* gA1 = A  + (size_t)(m0 + qa1 * 16 + lrow) * K + k0 + gslot;
    const short* gB0 = Bt + (size_t)(n0 + qa0 * 16 + lrow) * K + k0 + gslot;
    const short* gB1 = Bt + (size_t)(n0 + qa1 * 16 + lrow) * K + k0 + gslot;
    const short* lA0 = &As[0][qa0 * 512];
    const short* lA1 = &As[0][qa1 * 512];
    const short* lB0 = &Bs[0][qa0 * 512];
    const short* lB1 = &Bs[0][qa1 * 512];

    // fragment reads: wave quadrant (wr,wc), 4x4 16x16 subtiles
    int wr = (w >> 1) * 64, wc = (w & 1) * 64;
    int fr = lane & 15, kg = lane >> 4;
    int raoff = (wr + fr) * 32 + kg * 8;
    int rboff = (wc + fr) * 32 + kg * 8;

    int nsteps = KC >> 5;

    // prologue: stage buf 0
    stage16(gA0, lA0); stage16(gA1, lA1);
    stage16(gB0, lB0); stage16(gB1, lB1);
    __syncthreads();                      // drains vmcnt(0) before barrier

    f32x4 acc[4][4] = {};
    for (int s = 0; s < nsteps; ++s) {
        int cur = s & 1;
        if (s + 1 < nsteps) {             // issue next-tile loads BEFORE compute
            int nxt = cur ^ 1;
            int ks = (s + 1) * 32;
            stage16(gA0 + ks, lA0 + nxt * 4096);
            stage16(gA1 + ks, lA1 + nxt * 4096);
            stage16(gB0 + ks, lB0 + nxt * 4096);
            stage16(gB1 + ks, lB1 + nxt * 4096);
        }
        const short* ra = &As[cur][raoff];
        const short* rb = &Bs[cur][rboff];
        bf16x8 af[4], bm[4];
        #pragma unroll
        for (int i = 0; i < 4; i++) af[i] = *(const bf16x8*)(ra + i * 512);
        #pragma unroll
        for (int j = 0; j < 4; j++) bm[j] = *(const bf16x8*)(rb + j * 512);
        #pragma unroll
        for (int i = 0; i < 4; i++)
            #pragma unroll
            for (int j = 0; j < 4; j++)
                acc[i][j] = __builtin_amdgcn_mfma_f32_16x16x32_bf16(af[i], bm[j], acc[i][j], 0, 0, 0);
        __syncthreads();                  // one barrier/step; drains staging for next iter
    }

    float* base = part + (size_t)z * NBOX * FCDIM;
    #pragma unroll
    for (int i = 0; i < 4; i++)
        #pragma unroll
        for (int j = 0; j < 4; j++)
            #pragma unroll
            for (int r = 0; r < 4; r++) {
                int row = m0 + wr + i * 16 + kg * 4 + r;
                int col = n0 + wc + j * 16 + fr;
                base[(size_t)row * FCDIM + col] = acc[i][j][r];
            }
}

// ---------------- BN stage 1: sum split-K partials, per-block column stats ----------------
template<int NZ>
__global__ __launch_bounds__(256) void bn_stats1(
    const float* __restrict__ part, float* __restrict__ xsum, float* __restrict__ pstat)
{
    int tc = threadIdx.x & 63;
    int tr = threadIdx.x >> 6;
    int c  = blockIdx.x * 64 + tc;
    int r0 = blockIdx.y * 32;
    const size_t P = (size_t)NBOX * FCDIM;

    float s = 0.0f, q = 0.0f;
    #pragma unroll
    for (int rr = 0; rr < 8; rr++) {
        size_t o = (size_t)(r0 + tr + rr * 4) * FCDIM + c;
        float x = 0.0f;
        #pragma unroll
        for (int z = 0; z < NZ; z++) x += part[o + (size_t)z * P];
        xsum[o] = x;
        s += x; q += x * x;
    }
    __shared__ float Ss[4][64], Sq[4][64];
    Ss[tr][tc] = s; Sq[tr][tc] = q;
    __syncthreads();
    if (tr == 0) {
        float S = Ss[0][tc] + Ss[1][tc] + Ss[2][tc] + Ss[3][tc];
        float Q = Sq[0][tc] + Sq[1][tc] + Sq[2][tc] + Sq[3][tc];
        pstat[blockIdx.y * FCDIM + c] = S;
        pstat[16 * FCDIM + blockIdx.y * FCDIM + c] = Q;
    }
}

// ---------------- BN stage 2: finalize per-column scale/shift ----------------
__global__ __launch_bounds__(256) void bn_stats2(
    const float* __restrict__ pstat, const float* __restrict__ g,
    const float* __restrict__ be, float* __restrict__ scsh)
{
    int c = blockIdx.x * 256 + threadIdx.x;   // grid 4
    float S = 0.0f, Q = 0.0f;
    #pragma unroll
    for (int i = 0; i < 16; i++) {
        S += pstat[i * FCDIM + c];
        Q += pstat[16 * FCDIM + i * FCDIM + c];
    }
    float mu  = S * (1.0f / NBOX);
    float var = Q * (1.0f / NBOX) - mu * mu;
    float a = g[c] * rsqrtf(var + 1e-5f);
    scsh[c]         = a;
    scsh[FCDIM + c] = be[c] - mu * a;
}

// ---------------- BN apply (BN1): normalize + ReLU -> bf16 ----------------
__global__ __launch_bounds__(256) void bn_apply_bf(
    const float* __restrict__ xsum, const float* __restrict__ scsh,
    short* __restrict__ obf)
{
    size_t base = ((size_t)blockIdx.x * 256 + threadIdx.x) * 8;   // grid 256
    int c0 = (int)(base & (FCDIM - 1));
    float4 x0 = *(const float4*)(xsum + base);
    float4 x1 = *(const float4*)(xsum + base + 4);
    float4 a0 = *(const float4*)(scsh + c0);
    float4 a1 = *(const float4*)(scsh + c0 + 4);
    float4 b0 = *(const float4*)(scsh + FCDIM + c0);
    float4 b1 = *(const float4*)(scsh + FCDIM + c0 + 4);
    float r[8];
    r[0] = fmaxf(x0.x*a0.x + b0.x, 0.0f);
    r[1] = fmaxf(x0.y*a0.y + b0.y, 0.0f);
    r[2] = fmaxf(x0.z*a0.z + b0.z, 0.0f);
    r[3] = fmaxf(x0.w*a0.w + b0.w, 0.0f);
    r[4] = fmaxf(x1.x*a1.x + b1.x, 0.0f);
    r[5] = fmaxf(x1.y*a1.y + b1.y, 0.0f);
    r[6] = fmaxf(x1.z*a1.z + b1.z, 0.0f);
    r[7] = fmaxf(x1.w*a1.w + b1.w, 0.0f);
    union { unsigned short s[8]; i32x4 v; } u;
    #pragma unroll
    for (int i = 0; i < 8; i++) u.s[i] = f2bf(r[i]);
    *(i32x4*)(obf + base) = u.v;
}

// ---------------- fused BN2-apply + pred GEMV + bbox decode (consumes precomputed scsh) --------
__global__ __launch_bounds__(128) void bn2_pred_kernel(
    const float* __restrict__ xsum, const float* __restrict__ scsh,
    const float* __restrict__ pw, const float* __restrict__ pb,
    const float* __restrict__ bbox, const int* __restrict__ aid,
    const float* __restrict__ zp, float* __restrict__ out)
{
    int bn = blockIdx.x;
    int t  = threadIdx.x;
    __shared__ float xs[FCDIM];
    __shared__ float pr[OUTC];
    for (int i = t; i < FCDIM; i += 128)
        xs[i] = fmaxf(xsum[(size_t)bn * FCDIM + i] * scsh[i] + scsh[FCDIM + i], 0.0f);
    __syncthreads();

    float z = zp[bn];
    if (t < OUTC) {
        const float* wrow = pw + (size_t)t * FCDIM;
        float a = 0.0f;
        for (int k = 0; k < FCDIM; k += 4) {
            float4 w4 = *(const float4*)(wrow + k);
            a += xs[k] * w4.x + xs[k+1] * w4.y + xs[k+2] * w4.z + xs[k+3] * w4.w;
        }
        pr[t] = (a + pb[t]) * z;
    }
    __syncthreads();

    if (t < OUTC) {
        float y = bbox[bn*4+0], x = bbox[bn*4+1], h = bbox[bn*4+2], w = bbox[bn*4+3];
        int lvl = aid[bn] / 3;
        float st = 4.0f * exp2f((float)lvl * z);
        float o;
        if (t < 24) {
            int k = t / 6, j = t - k * 6;
            const float* d = &pr[5 + k * 6];
            switch (j) {
                case 0:  o = y + d[0] * h;  break;
                case 1:  o = x + d[1] * w;  break;
                case 2:  o = d[4] * st;     break;
                case 3:  o = h * expf(d[2]); break;
                case 4:  o = w * expf(d[3]); break;
                default: o = expf(d[5]) * st; break;
            }
        } else if (t < 29) {
            float m = pr[0];
            #pragma unroll
            for (int i = 1; i < 5; i++) m = fmaxf(m, pr[i]);
            float den = 0.0f;
            #pragma unroll
            for (int i = 0; i < 5; i++) den += expf(pr[i] - m);
            o = expf(pr[t - 24] - m) / den;
        } else if (t < 61) {
            int i = t - 29, k = i >> 3;
            const float* qq = &pr[29 + k * 8];
            float m = qq[0];
            #pragma unroll
            for (int ii = 1; ii < 8; ii++) m = fmaxf(m, qq[ii]);
            float den = 0.0f;
            #pragma unroll
            for (int ii = 0; ii < 8; ii++) den += expf(qq[ii] - m);
            o = expf(pr[t] - m) / den;
        } else {
            o = 1.0f / (1.0f + expf(-pr[t])) * 0.6f - 0.3f;
        }
        out[(size_t)bn * OUTC + t] = o;
    }
}

extern "C" void kernel_launch(void* const* d_in, const int* in_sizes, int n_in,
                              void* d_out, int out_size, void* d_ws, size_t ws_size,
                              hipStream_t stream)
{
    const float* f0   = (const float*)d_in[0];
    const float* f1   = (const float*)d_in[1];
    const float* f2   = (const float*)d_in[2];
    const float* f3   = (const float*)d_in[3];
    const float* bbox = (const float*)d_in[4];
    const int*   aid  = (const int*)d_in[5];
    const float* zp   = (const float*)d_in[6];
    const float* fc1w = (const float*)d_in[7];
    const float* bn1g = (const float*)d_in[9];
    const float* bn1b = (const float*)d_in[10];
    const float* fc2w = (const float*)d_in[11];
    const float* bn2g = (const float*)d_in[13];
    const float* bn2b = (const float*)d_in[14];
    const float* pw   = (const float*)d_in[15];
    const float* pb   = (const float*)d_in[16];
    float* out = (float*)d_out;

    // workspace layout (linear, ~145.4 MB of the 256 MiB ws)
    char* ws = (char*)d_ws;
    short* pooled = (short*)(ws);                    // 12,845,056
    short* gt0    = (short*)(ws + 13631488);         // 16,777,216
    short* gt1    = (short*)(ws + 30408704);         //  4,194,304
    short* gt2    = (short*)(ws + 34603008);         //  1,048,576
    short* gt3    = (short*)(ws + 35651584);         //    262,144
    short* w1     = (short*)(ws + 36700160);         // 25,690,112
    short* w2     = (short*)(ws + 62390272);         //  2,097,152
    float* part1  = (float*)(ws + 64487424);         // Z1 * 2,097,152 = 29,360,128
    float* part2  = (float*)(ws + 123207680);        // Z2 * 2,097,152 = 16,777,216
    float* xsum   = (float*)(ws + 139984896);        //  2,097,152
    short* x1n    = (short*)(ws + 142082048);        //  1,048,576
    float* pstat  = (float*)(ws + 145227776);        //    131,072
    float* scsh   = (float*)(ws + 145358848);        //      8,192

    // 1 merged streaming launch: transpose (1360) + w1 cast (6272) + w2 cast (512)
    stream_prep_kernel<<<1360 + 6272 + 512, 256, 0, stream>>>(
        f0, f1, f2, f3, gt0, gt1, gt2, gt3, fc1w, w1, fc2w, w2);

    roi_kernel<<<NBOX, 512, 0, stream>>>(gt0, gt1, gt2, gt3, bbox, aid, pooled);

    gemm_db<<<4 * 8 * Z1, 256, 0, stream>>>(pooled, w1, part1, K1, K1 / Z1, 8 * Z1);

    bn_stats1<Z1><<<dim3(16, 16), 256, 0, stream>>>(part1, xsum, pstat);
    bn_stats2<<<4, 256, 0, stream>>>(pstat, bn1g, bn1b, scsh);
    bn_apply_bf<<<256, 256, 0, stream>>>(xsum, scsh, x1n);

    gemm_db<<<4 * 8 * Z2, 256, 0, stream>>>(x1n, w2, part2, FCDIM, FCDIM / Z2, 8 * Z2);

    bn_stats1<Z2><<<dim3(16, 16), 256, 0, stream>>>(part2, xsum, pstat);
    bn_stats2<<<4, 256, 0, stream>>>(pstat, bn2g, bn2b, scsh);

    bn2_pred_kernel<<<NBOX, 128, 0, stream>>>(xsum, scsh, pw, pb, bbox, aid, zp, out);
}